// Round 1
// baseline (888.425 us; speedup 1.0000x reference)
//
#include <hip/hip_runtime.h>
#include <hip/hip_bf16.h>
#include <math.h>

#define NTOK 8192
#define DDIM 1024
#define HDIM 4096
#define NEXP 8
#define KTOP 2
#define MAXROWS 17408   /* 16384 + 8*128 */
#define MAXTILES 136

typedef __bf16 bf16x8 __attribute__((ext_vector_type(8)));
typedef float f32x4 __attribute__((ext_vector_type(4)));

#define GAS __attribute__((address_space(1)))
#define LAS __attribute__((address_space(3)))

__device__ __forceinline__ void async16(const void* g, void* l) {
  __builtin_amdgcn_global_load_lds((GAS void*)g, (LAS void*)l, 16, 0, 0);
}

// ---------------- workspace layout (bytes) ----------------
#define XB_OFF     ((size_t)0)
#define W1T_OFF    (XB_OFF + (size_t)NTOK*DDIM*2)
#define W2T_OFF    (W1T_OFF + (size_t)NEXP*DDIM*HDIM*2)
#define HB_OFF     (W2T_OFF + (size_t)NEXP*HDIM*DDIM*2)
#define ROWTOK_OFF (HB_OFF + (size_t)MAXROWS*HDIM*2)
#define ROWW_OFF   (ROWTOK_OFF + (size_t)MAXROWS*4)
#define TOKE_OFF   (ROWW_OFF + (size_t)MAXROWS*4)
#define TOKW_OFF   (TOKE_OFF + (size_t)NTOK*KTOP*4)
#define TILEE_OFF  (TOKW_OFF + (size_t)NTOK*KTOP*4)
#define CNT_OFF    (TILEE_OFF + (size_t)256*4)
#define POS_OFF    (CNT_OFF + 64)
#define IMP_OFF    (POS_OFF + 64)
#define META_OFF   (IMP_OFF + 64)

// ---------------- small utility kernels ----------------
__global__ void init_kernel(int* counts, float* importance) {
  if (threadIdx.x < NEXP) { counts[threadIdx.x] = 0; importance[threadIdx.x] = 0.f; }
}

__global__ void zero_out_kernel(float* __restrict__ out) {
  size_t i = ((size_t)blockIdx.x * blockDim.x + threadIdx.x) * 4;
  if (i < (size_t)NTOK * DDIM) {
    *(float4*)(out + i) = make_float4(0.f, 0.f, 0.f, 0.f);
  }
}

__global__ void cast_x_kernel(const float* __restrict__ src, __hip_bfloat16* __restrict__ dst) {
  size_t i = ((size_t)blockIdx.x * blockDim.x + threadIdx.x) * 4;
  if (i < (size_t)NTOK * DDIM) {
    float4 v = *(const float4*)(src + i);
    dst[i + 0] = __float2bfloat16(v.x);
    dst[i + 1] = __float2bfloat16(v.y);
    dst[i + 2] = __float2bfloat16(v.z);
    dst[i + 3] = __float2bfloat16(v.w);
  }
}

// per-expert transpose+cast: src [E][R][C] fp32 -> dst [E][C][R] bf16
__global__ __launch_bounds__(256) void transpose_cast_kernel(
    const float* __restrict__ src, __hip_bfloat16* __restrict__ dst, int R, int C) {
  __shared__ float tile[64][65];
  const int e = blockIdx.z;
  const float* s = src + (size_t)e * R * C;
  __hip_bfloat16* d = dst + (size_t)e * R * C;
  const int c0 = blockIdx.x * 64, r0 = blockIdx.y * 64;
  const int tx = threadIdx.x & 63, ty = threadIdx.x >> 6;
#pragma unroll
  for (int i = ty; i < 64; i += 4)
    tile[i][tx] = s[(size_t)(r0 + i) * C + c0 + tx];
  __syncthreads();
#pragma unroll
  for (int i = ty; i < 64; i += 4)
    d[(size_t)(c0 + i) * R + r0 + tx] = __float2bfloat16(tile[tx][i]);
}

// ---------------- gating ----------------
// one wave handles 8 tokens; lane = token_sub*8 + expert
__global__ __launch_bounds__(256) void gating_kernel(
    const float* __restrict__ x, const float* __restrict__ Wg, const float* __restrict__ bg,
    int* __restrict__ tok_e, float* __restrict__ tok_w,
    int* __restrict__ counts, float* __restrict__ importance) {
  const int tid = threadIdx.x, wid = tid >> 6, lane = tid & 63;
  const int t = blockIdx.x * 32 + wid * 8 + (lane >> 3);
  const int e = lane & 7;
  const float* xr = x + (size_t)t * DDIM;
  double dot = 0.0;
  for (int d = 0; d < DDIM; d += 4) {
    float4 xv = *(const float4*)(xr + d);
    dot += (double)xv.x * (double)Wg[(d + 0) * NEXP + e];
    dot += (double)xv.y * (double)Wg[(d + 1) * NEXP + e];
    dot += (double)xv.z * (double)Wg[(d + 2) * NEXP + e];
    dot += (double)xv.w * (double)Wg[(d + 3) * NEXP + e];
  }
  double logit = dot + (double)bg[e];
  // softmax over the 8-lane group (xor stays within group)
  double m = logit;
  for (int off = 1; off < 8; off <<= 1) {
    double o = __shfl_xor(m, off, 64);
    m = o > m ? o : m;
  }
  double p = exp(logit - m);
  double s = p;
  for (int off = 1; off < 8; off <<= 1) s += __shfl_xor(s, off, 64);
  float prob = (float)(p / s);

  __shared__ float imp[NEXP];
  __shared__ int cnt[NEXP];
  if (tid < NEXP) { imp[tid] = 0.f; cnt[tid] = 0; }
  __syncthreads();
  atomicAdd(&imp[e], prob);

  // argmax (tie -> lower index, matching top_k)
  float bp = prob; int be = e;
  for (int off = 1; off < 8; off <<= 1) {
    float op = __shfl_xor(bp, off, 64); int oe = __shfl_xor(be, off, 64);
    if (op > bp || (op == bp && oe < be)) { bp = op; be = oe; }
  }
  float p2 = (e == be) ? -1.f : prob;
  float sp = p2; int se = e;
  for (int off = 1; off < 8; off <<= 1) {
    float op = __shfl_xor(sp, off, 64); int oe = __shfl_xor(se, off, 64);
    if (op > sp || (op == sp && oe < se)) { sp = op; se = oe; }
  }
  if (e == 0) {
    float tsum = bp + sp;
    tok_e[t * 2 + 0] = be; tok_e[t * 2 + 1] = se;
    tok_w[t * 2 + 0] = bp / tsum; tok_w[t * 2 + 1] = sp / tsum;
    atomicAdd(&cnt[be], 1); atomicAdd(&cnt[se], 1);
  }
  __syncthreads();
  if (tid < NEXP) {
    atomicAdd(&counts[tid], cnt[tid]);
    atomicAdd(&importance[tid], imp[tid]);
  }
}

// ---------------- routing ----------------
__global__ void offsets_kernel(const int* __restrict__ counts, int* pos, int* tile_expert,
                               int* meta, int* row_token) {
  if (threadIdx.x == 0) {
    int pb = 0, tb = 0;
    for (int e = 0; e < NEXP; e++) {
      pos[e] = pb;
      int tiles = (counts[e] + 127) >> 7;
      for (int tt = 0; tt < tiles; ++tt) tile_expert[tb + tt] = e;
      pb += tiles * 128; tb += tiles;
    }
    meta[0] = tb;  // num_row_tiles
  }
  __syncthreads();
  for (int i = threadIdx.x; i < MAXROWS; i += blockDim.x) row_token[i] = -1;
}

__global__ void scatter_kernel(const int* __restrict__ tok_e, const float* __restrict__ tok_w,
                               int* __restrict__ pos, int* __restrict__ row_token,
                               float* __restrict__ row_weight) {
  __shared__ int lcnt[NEXP], lbase[NEXP];
  const int t = blockIdx.x * 256 + threadIdx.x;
  if (threadIdx.x < NEXP) lcnt[threadIdx.x] = 0;
  __syncthreads();
  const int e0 = tok_e[t * 2 + 0], e1 = tok_e[t * 2 + 1];
  const int s0 = atomicAdd(&lcnt[e0], 1);
  const int s1 = atomicAdd(&lcnt[e1], 1);
  __syncthreads();
  if (threadIdx.x < NEXP) lbase[threadIdx.x] = atomicAdd(&pos[threadIdx.x], lcnt[threadIdx.x]);
  __syncthreads();
  int r0 = lbase[e0] + s0; row_token[r0] = t; row_weight[r0] = tok_w[t * 2 + 0];
  int r1 = lbase[e1] + s1; row_token[r1] = t; row_weight[r1] = tok_w[t * 2 + 1];
}

// ---------------- GEMM1: h = relu(x @ W1[e] + b1[e]) ----------------
// A: gathered token rows (bf16 [NTOK][D]); B: W1t bf16 [E][H][D]; C: hb bf16 [MAXROWS][H]
__global__ __launch_bounds__(256) void gemm1_kernel(
    const __hip_bfloat16* __restrict__ xb, const __hip_bfloat16* __restrict__ w1t,
    const float* __restrict__ b1, __hip_bfloat16* __restrict__ hb,
    const int* __restrict__ row_token, const int* __restrict__ tile_expert,
    const int* __restrict__ meta) {
  const int tile_y = blockIdx.y;
  if (tile_y >= meta[0]) return;
  const int n0 = blockIdx.x * 128;
  const int e = tile_expert[tile_y];
  const int r0 = tile_y * 128;
  const int tid = threadIdx.x;
  const int wid = tid >> 6, lane = tid & 63;

  __shared__ __align__(16) __hip_bfloat16 As[128 * 32];
  __shared__ __align__(16) __hip_bfloat16 Bs[128 * 32];

  const int srow = wid * 32 + (lane >> 2);
  const int scol = (lane & 3) * 8;
  int t0 = row_token[r0 + srow];      if (t0 < 0) t0 = 0;
  int t1 = row_token[r0 + srow + 16]; if (t1 < 0) t1 = 0;
  const __hip_bfloat16* ga0 = xb + (size_t)t0 * DDIM + scol;
  const __hip_bfloat16* ga1 = xb + (size_t)t1 * DDIM + scol;
  const __hip_bfloat16* gb0 = w1t + ((size_t)e * HDIM + n0 + srow) * DDIM + scol;
  const __hip_bfloat16* gb1 = gb0 + (size_t)16 * DDIM;
  __hip_bfloat16* lA0 = &As[(wid * 32 + 0) * 32];
  __hip_bfloat16* lA1 = &As[(wid * 32 + 16) * 32];
  __hip_bfloat16* lB0 = &Bs[(wid * 32 + 0) * 32];
  __hip_bfloat16* lB1 = &Bs[(wid * 32 + 16) * 32];

  f32x4 acc[4][4] = {};
  const int wm = (wid & 1) * 64, wn = (wid >> 1) * 64;
  const int fr = lane & 15;
  const int kq = (lane >> 4) * 8;

  for (int kt = 0; kt < DDIM / 32; ++kt) {
    __syncthreads();
    async16(ga0, lA0); async16(ga1, lA1);
    async16(gb0, lB0); async16(gb1, lB1);
    ga0 += 32; ga1 += 32; gb0 += 32; gb1 += 32;
    __syncthreads();
    bf16x8 av[4], bv[4];
#pragma unroll
    for (int i = 0; i < 4; i++) av[i] = *(const bf16x8*)&As[(wm + i * 16 + fr) * 32 + kq];
#pragma unroll
    for (int j = 0; j < 4; j++) bv[j] = *(const bf16x8*)&Bs[(wn + j * 16 + fr) * 32 + kq];
#pragma unroll
    for (int i = 0; i < 4; i++)
#pragma unroll
      for (int j = 0; j < 4; j++)
        acc[i][j] = __builtin_amdgcn_mfma_f32_16x16x32_bf16(av[i], bv[j], acc[i][j], 0, 0, 0);
  }

  const int crow = (lane >> 4) * 4;
  const int ccol = lane & 15;
#pragma unroll
  for (int j = 0; j < 4; j++) {
    const int gc = n0 + wn + j * 16 + ccol;
    const float bias = b1[e * HDIM + gc];
#pragma unroll
    for (int i = 0; i < 4; i++) {
      const int grb = r0 + wm + i * 16 + crow;
#pragma unroll
      for (int r = 0; r < 4; r++) {
        float v = acc[i][j][r] + bias;
        v = v > 0.f ? v : 0.f;
        hb[(size_t)(grb + r) * HDIM + gc] = __float2bfloat16(v);
      }
    }
  }
}

// ---------------- GEMM2: out[token] += w * (h @ W2[e] + b2[e]) ----------------
__global__ __launch_bounds__(256) void gemm2_kernel(
    const __hip_bfloat16* __restrict__ hb, const __hip_bfloat16* __restrict__ w2t,
    const float* __restrict__ b2, float* __restrict__ out,
    const int* __restrict__ row_token, const float* __restrict__ row_weight,
    const int* __restrict__ tile_expert, const int* __restrict__ meta) {
  const int tile_y = blockIdx.y;
  if (tile_y >= meta[0]) return;
  const int n0 = blockIdx.x * 128;
  const int e = tile_expert[tile_y];
  const int r0 = tile_y * 128;
  const int tid = threadIdx.x;
  const int wid = tid >> 6, lane = tid & 63;

  __shared__ __align__(16) __hip_bfloat16 As[128 * 32];
  __shared__ __align__(16) __hip_bfloat16 Bs[128 * 32];

  const int srow = wid * 32 + (lane >> 2);
  const int scol = (lane & 3) * 8;
  const __hip_bfloat16* ga0 = hb + (size_t)(r0 + srow) * HDIM + scol;
  const __hip_bfloat16* ga1 = ga0 + (size_t)16 * HDIM;
  const __hip_bfloat16* gb0 = w2t + ((size_t)e * DDIM + n0 + srow) * HDIM + scol;
  const __hip_bfloat16* gb1 = gb0 + (size_t)16 * HDIM;
  __hip_bfloat16* lA0 = &As[(wid * 32 + 0) * 32];
  __hip_bfloat16* lA1 = &As[(wid * 32 + 16) * 32];
  __hip_bfloat16* lB0 = &Bs[(wid * 32 + 0) * 32];
  __hip_bfloat16* lB1 = &Bs[(wid * 32 + 16) * 32];

  f32x4 acc[4][4] = {};
  const int wm = (wid & 1) * 64, wn = (wid >> 1) * 64;
  const int fr = lane & 15;
  const int kq = (lane >> 4) * 8;

  for (int kt = 0; kt < HDIM / 32; ++kt) {
    __syncthreads();
    async16(ga0, lA0); async16(ga1, lA1);
    async16(gb0, lB0); async16(gb1, lB1);
    ga0 += 32; ga1 += 32; gb0 += 32; gb1 += 32;
    __syncthreads();
    bf16x8 av[4], bv[4];
#pragma unroll
    for (int i = 0; i < 4; i++) av[i] = *(const bf16x8*)&As[(wm + i * 16 + fr) * 32 + kq];
#pragma unroll
    for (int j = 0; j < 4; j++) bv[j] = *(const bf16x8*)&Bs[(wn + j * 16 + fr) * 32 + kq];
#pragma unroll
    for (int i = 0; i < 4; i++)
#pragma unroll
      for (int j = 0; j < 4; j++)
        acc[i][j] = __builtin_amdgcn_mfma_f32_16x16x32_bf16(av[i], bv[j], acc[i][j], 0, 0, 0);
  }

  const int crow = (lane >> 4) * 4;
  const int ccol = lane & 15;
#pragma unroll
  for (int i = 0; i < 4; i++) {
#pragma unroll
    for (int r = 0; r < 4; r++) {
      const int rr = r0 + wm + i * 16 + crow + r;
      const int tok = row_token[rr];
      if (tok < 0) continue;
      const float w = row_weight[rr];
#pragma unroll
      for (int j = 0; j < 4; j++) {
        const int gc = n0 + wn + j * 16 + ccol;
        float v = w * (acc[i][j][r] + b2[e * DDIM + gc]);
        atomicAdd(out + (size_t)tok * DDIM + gc, v);
      }
    }
  }
}

// ---------------- lb_loss ----------------
__global__ void finalize_kernel(const float* __restrict__ importance,
                                const int* __restrict__ counts, float* __restrict__ lb_out) {
  if (threadIdx.x == 0 && blockIdx.x == 0) {
    float s = 0.f;
    for (int e = 0; e < NEXP; e++) s += importance[e];
    float lb = 0.f;
    for (int e = 0; e < NEXP; e++)
      lb += (importance[e] / s) * ((float)counts[e] / (float)(NTOK * KTOP));
    lb_out[0] = (float)NEXP * lb;
  }
}

// ---------------- launch ----------------
extern "C" void kernel_launch(void* const* d_in, const int* in_sizes, int n_in,
                              void* d_out, int out_size, void* d_ws, size_t ws_size,
                              hipStream_t stream) {
  (void)in_sizes; (void)n_in; (void)out_size; (void)ws_size;
  const float* x  = (const float*)d_in[0];
  const float* Wg = (const float*)d_in[1];
  const float* bg = (const float*)d_in[2];
  const float* W1 = (const float*)d_in[3];
  const float* b1 = (const float*)d_in[4];
  const float* W2 = (const float*)d_in[5];
  const float* b2 = (const float*)d_in[6];
  float* out = (float*)d_out;

  char* ws = (char*)d_ws;
  __hip_bfloat16* xb  = (__hip_bfloat16*)(ws + XB_OFF);
  __hip_bfloat16* w1t = (__hip_bfloat16*)(ws + W1T_OFF);
  __hip_bfloat16* w2t = (__hip_bfloat16*)(ws + W2T_OFF);
  __hip_bfloat16* hb  = (__hip_bfloat16*)(ws + HB_OFF);
  int*   row_token  = (int*)(ws + ROWTOK_OFF);
  float* row_weight = (float*)(ws + ROWW_OFF);
  int*   tok_e  = (int*)(ws + TOKE_OFF);
  float* tok_w  = (float*)(ws + TOKW_OFF);
  int*   tile_e = (int*)(ws + TILEE_OFF);
  int*   counts = (int*)(ws + CNT_OFF);
  int*   pos    = (int*)(ws + POS_OFF);
  float* importance = (float*)(ws + IMP_OFF);
  int*   meta   = (int*)(ws + META_OFF);

  init_kernel<<<1, 64, 0, stream>>>(counts, importance);
  zero_out_kernel<<<NTOK * DDIM / 4 / 256, 256, 0, stream>>>(out);
  cast_x_kernel<<<NTOK * DDIM / 4 / 256, 256, 0, stream>>>(x, xb);
  transpose_cast_kernel<<<dim3(HDIM / 64, DDIM / 64, NEXP), 256, 0, stream>>>(W1, w1t, DDIM, HDIM);
  transpose_cast_kernel<<<dim3(DDIM / 64, HDIM / 64, NEXP), 256, 0, stream>>>(W2, w2t, HDIM, DDIM);
  gating_kernel<<<NTOK / 32, 256, 0, stream>>>(x, Wg, bg, tok_e, tok_w, counts, importance);
  offsets_kernel<<<1, 256, 0, stream>>>(counts, pos, tile_e, meta, row_token);
  scatter_kernel<<<NTOK / 256, 256, 0, stream>>>(tok_e, tok_w, pos, row_token, row_weight);
  gemm1_kernel<<<dim3(HDIM / 128, MAXTILES), 256, 0, stream>>>(xb, w1t, b1, hb, row_token, tile_e, meta);
  gemm2_kernel<<<dim3(DDIM / 128, MAXTILES), 256, 0, stream>>>(hb, w2t, b2, out, row_token, row_weight, tile_e, meta);
  finalize_kernel<<<1, 64, 0, stream>>>(importance, counts, out + (size_t)NTOK * DDIM);
}

// Round 2
// 861.433 us; speedup vs baseline: 1.0313x; 1.0313x over previous
//
#include <hip/hip_runtime.h>
#include <hip/hip_bf16.h>
#include <math.h>

#define NTOK 8192
#define DDIM 1024
#define HDIM 4096
#define NEXP 8
#define KTOP 2
#define MAXROWS 17408   /* 16384 + 8*128 */
#define MAXTILES 136

typedef __bf16 bf16x8 __attribute__((ext_vector_type(8)));
typedef float f32x4 __attribute__((ext_vector_type(4)));

#define GAS __attribute__((address_space(1)))
#define LAS __attribute__((address_space(3)))

__device__ __forceinline__ void async16(const void* g, void* l) {
  __builtin_amdgcn_global_load_lds((GAS void*)g, (LAS void*)l, 16, 0, 0);
}

// ---------------- workspace layout (bytes) ----------------
#define XB_OFF     ((size_t)0)
#define W1T_OFF    (XB_OFF + (size_t)NTOK*DDIM*2)
#define ROWOUT_OFF W1T_OFF              /* w1t dead after gemm1; rowout 35.7MB < 64MB */
#define W2T_OFF    (W1T_OFF + (size_t)NEXP*DDIM*HDIM*2)
#define HB_OFF     (W2T_OFF + (size_t)NEXP*HDIM*DDIM*2)
#define ROWTOK_OFF (HB_OFF + (size_t)MAXROWS*HDIM*2)
#define ROWW_OFF   (ROWTOK_OFF + (size_t)MAXROWS*4)
#define TOKE_OFF   (ROWW_OFF + (size_t)MAXROWS*4)
#define TOKW_OFF   (TOKE_OFF + (size_t)NTOK*KTOP*4)
#define TOKROW_OFF (TOKW_OFF + (size_t)NTOK*KTOP*4)
#define TILEE_OFF  (TOKROW_OFF + (size_t)NTOK*KTOP*4)
#define CNT_OFF    (TILEE_OFF + (size_t)256*4)
#define POS_OFF    (CNT_OFF + 64)
#define IMP_OFF    (POS_OFF + 64)
#define META_OFF   (IMP_OFF + 64)

// ---------------- small utility kernels ----------------
__global__ void init_kernel(int* counts, float* importance) {
  if (threadIdx.x < NEXP) { counts[threadIdx.x] = 0; importance[threadIdx.x] = 0.f; }
}

__global__ void cast_x_kernel(const float* __restrict__ src, __hip_bfloat16* __restrict__ dst) {
  size_t i = ((size_t)blockIdx.x * blockDim.x + threadIdx.x) * 4;
  if (i < (size_t)NTOK * DDIM) {
    float4 v = *(const float4*)(src + i);
    dst[i + 0] = __float2bfloat16(v.x);
    dst[i + 1] = __float2bfloat16(v.y);
    dst[i + 2] = __float2bfloat16(v.z);
    dst[i + 3] = __float2bfloat16(v.w);
  }
}

// per-expert transpose+cast: src [E][R][C] fp32 -> dst [E][C][R] bf16
__global__ __launch_bounds__(256) void transpose_cast_kernel(
    const float* __restrict__ src, __hip_bfloat16* __restrict__ dst, int R, int C) {
  __shared__ float tile[64][65];
  const int e = blockIdx.z;
  const float* s = src + (size_t)e * R * C;
  __hip_bfloat16* d = dst + (size_t)e * R * C;
  const int c0 = blockIdx.x * 64, r0 = blockIdx.y * 64;
  // read phase: thread reads float4; 16 rows per pass, 4 passes
  const int tc = (threadIdx.x & 15) * 4;
  const int tr = threadIdx.x >> 4;
#pragma unroll
  for (int p = 0; p < 4; ++p) {
    float4 v = *(const float4*)&s[(size_t)(r0 + tr + p * 16) * C + c0 + tc];
    tile[tr + p * 16][tc + 0] = v.x;
    tile[tr + p * 16][tc + 1] = v.y;
    tile[tr + p * 16][tc + 2] = v.z;
    tile[tr + p * 16][tc + 3] = v.w;
  }
  __syncthreads();
  // write phase: thread writes 4 consecutive R-elements of one out-row (ushort4)
  const int oc = threadIdx.x >> 4;
  const int orr = (threadIdx.x & 15) * 4;
#pragma unroll
  for (int p = 0; p < 4; ++p) {
    const int c = oc + p * 16;
    __hip_bfloat16 tmp[4];
    tmp[0] = __float2bfloat16(tile[orr + 0][c]);
    tmp[1] = __float2bfloat16(tile[orr + 1][c]);
    tmp[2] = __float2bfloat16(tile[orr + 2][c]);
    tmp[3] = __float2bfloat16(tile[orr + 3][c]);
    *(ushort4*)&d[(size_t)(c0 + c) * R + r0 + orr] = *(ushort4*)tmp;
  }
}

// ---------------- gating ----------------
__global__ __launch_bounds__(256) void gating_kernel(
    const float* __restrict__ x, const float* __restrict__ Wg, const float* __restrict__ bg,
    int* __restrict__ tok_e, float* __restrict__ tok_w,
    int* __restrict__ counts, float* __restrict__ importance) {
  const int tid = threadIdx.x, wid = tid >> 6, lane = tid & 63;
  const int t = blockIdx.x * 32 + wid * 8 + (lane >> 3);
  const int e = lane & 7;
  const float* xr = x + (size_t)t * DDIM;
  double dot = 0.0;
  for (int d = 0; d < DDIM; d += 4) {
    float4 xv = *(const float4*)(xr + d);
    dot += (double)xv.x * (double)Wg[(d + 0) * NEXP + e];
    dot += (double)xv.y * (double)Wg[(d + 1) * NEXP + e];
    dot += (double)xv.z * (double)Wg[(d + 2) * NEXP + e];
    dot += (double)xv.w * (double)Wg[(d + 3) * NEXP + e];
  }
  double logit = dot + (double)bg[e];
  double m = logit;
  for (int off = 1; off < 8; off <<= 1) {
    double o = __shfl_xor(m, off, 64);
    m = o > m ? o : m;
  }
  double p = exp(logit - m);
  double s = p;
  for (int off = 1; off < 8; off <<= 1) s += __shfl_xor(s, off, 64);
  float prob = (float)(p / s);

  __shared__ float imp[NEXP];
  __shared__ int cnt[NEXP];
  if (tid < NEXP) { imp[tid] = 0.f; cnt[tid] = 0; }
  __syncthreads();
  atomicAdd(&imp[e], prob);

  float bp = prob; int be = e;
  for (int off = 1; off < 8; off <<= 1) {
    float op = __shfl_xor(bp, off, 64); int oe = __shfl_xor(be, off, 64);
    if (op > bp || (op == bp && oe < be)) { bp = op; be = oe; }
  }
  float p2 = (e == be) ? -1.f : prob;
  float sp = p2; int se = e;
  for (int off = 1; off < 8; off <<= 1) {
    float op = __shfl_xor(sp, off, 64); int oe = __shfl_xor(se, off, 64);
    if (op > sp || (op == sp && oe < se)) { sp = op; se = oe; }
  }
  if (e == 0) {
    float tsum = bp + sp;
    tok_e[t * 2 + 0] = be; tok_e[t * 2 + 1] = se;
    tok_w[t * 2 + 0] = bp / tsum; tok_w[t * 2 + 1] = sp / tsum;
    atomicAdd(&cnt[be], 1); atomicAdd(&cnt[se], 1);
  }
  __syncthreads();
  if (tid < NEXP) {
    atomicAdd(&counts[tid], cnt[tid]);
    atomicAdd(&importance[tid], imp[tid]);
  }
}

// ---------------- routing ----------------
__global__ void offsets_kernel(const int* __restrict__ counts, int* pos, int* tile_expert,
                               int* meta, int* row_token) {
  if (threadIdx.x == 0) {
    int pb = 0, tb = 0;
    for (int e = 0; e < NEXP; e++) {
      pos[e] = pb;
      int tiles = (counts[e] + 127) >> 7;
      for (int tt = 0; tt < tiles; ++tt) tile_expert[tb + tt] = e;
      pb += tiles * 128; tb += tiles;
    }
    meta[0] = tb;
  }
  __syncthreads();
  for (int i = threadIdx.x; i < MAXROWS; i += blockDim.x) row_token[i] = -1;
}

__global__ void scatter_kernel(const int* __restrict__ tok_e, const float* __restrict__ tok_w,
                               int* __restrict__ pos, int* __restrict__ row_token,
                               float* __restrict__ row_weight, int* __restrict__ tok_row) {
  __shared__ int lcnt[NEXP], lbase[NEXP];
  const int t = blockIdx.x * 256 + threadIdx.x;
  if (threadIdx.x < NEXP) lcnt[threadIdx.x] = 0;
  __syncthreads();
  const int e0 = tok_e[t * 2 + 0], e1 = tok_e[t * 2 + 1];
  const int s0 = atomicAdd(&lcnt[e0], 1);
  const int s1 = atomicAdd(&lcnt[e1], 1);
  __syncthreads();
  if (threadIdx.x < NEXP) lbase[threadIdx.x] = atomicAdd(&pos[threadIdx.x], lcnt[threadIdx.x]);
  __syncthreads();
  int r0 = lbase[e0] + s0; row_token[r0] = t; row_weight[r0] = tok_w[t * 2 + 0]; tok_row[t * 2 + 0] = r0;
  int r1 = lbase[e1] + s1; row_token[r1] = t; row_weight[r1] = tok_w[t * 2 + 1]; tok_row[t * 2 + 1] = r1;
}

// ---------------- GEMM1: h = relu(x @ W1[e] + b1[e]), BK=64, swizzled LDS ----------------
__global__ __launch_bounds__(256) void gemm1_kernel(
    const __hip_bfloat16* __restrict__ xb, const __hip_bfloat16* __restrict__ w1t,
    const float* __restrict__ b1, __hip_bfloat16* __restrict__ hb,
    const int* __restrict__ row_token, const int* __restrict__ tile_expert,
    const int* __restrict__ meta) {
  const int tile_y = blockIdx.y;
  if (tile_y >= meta[0]) return;
  const int n0 = blockIdx.x * 128;
  const int e = tile_expert[tile_y];
  const int r0 = tile_y * 128;
  const int tid = threadIdx.x;
  const int wid = tid >> 6, lane = tid & 63;

  __shared__ __align__(16) __hip_bfloat16 As[128 * 64];
  __shared__ __align__(16) __hip_bfloat16 Bs[128 * 64];

  const int lrow = lane >> 3;                       // 0..7
  const int g = ((lane & 7) ^ lrow) * 8;            // swizzled 16B-group (elements)
  const __hip_bfloat16* ga[4]; const __hip_bfloat16* gb[4];
  __hip_bfloat16 *lA[4], *lB[4];
#pragma unroll
  for (int c = 0; c < 4; ++c) {
    const int srow = wid * 32 + c * 8 + lrow;
    int t = row_token[r0 + srow]; if (t < 0) t = 0;
    ga[c] = xb + (size_t)t * DDIM + g;
    gb[c] = w1t + ((size_t)e * HDIM + n0 + srow) * DDIM + g;
    lA[c] = &As[(wid * 32 + c * 8) * 64];
    lB[c] = &Bs[(wid * 32 + c * 8) * 64];
  }

  f32x4 acc[4][4] = {};
  const int wm = (wid & 1) * 64, wn = (wid >> 1) * 64;
  const int fr = lane & 15;
  const int swz0 = ((0 + (lane >> 4)) ^ (lane & 7)) * 8;
  const int swz1 = ((4 + (lane >> 4)) ^ (lane & 7)) * 8;

  for (int kt = 0; kt < DDIM / 64; ++kt) {
    __syncthreads();
#pragma unroll
    for (int c = 0; c < 4; ++c) {
      async16(ga[c], lA[c]); async16(gb[c], lB[c]);
      ga[c] += 64; gb[c] += 64;
    }
    __syncthreads();
#pragma unroll
    for (int ks = 0; ks < 2; ++ks) {
      const int off = ks ? swz1 : swz0;
      bf16x8 av[4], bv[4];
#pragma unroll
      for (int i = 0; i < 4; i++) av[i] = *(const bf16x8*)&As[(wm + i * 16 + fr) * 64 + off];
#pragma unroll
      for (int j = 0; j < 4; j++) bv[j] = *(const bf16x8*)&Bs[(wn + j * 16 + fr) * 64 + off];
#pragma unroll
      for (int i = 0; i < 4; i++)
#pragma unroll
        for (int j = 0; j < 4; j++)
          acc[i][j] = __builtin_amdgcn_mfma_f32_16x16x32_bf16(av[i], bv[j], acc[i][j], 0, 0, 0);
    }
  }

  const int crow = (lane >> 4) * 4;
  const int ccol = lane & 15;
#pragma unroll
  for (int j = 0; j < 4; j++) {
    const int gc = n0 + wn + j * 16 + ccol;
    const float bias = b1[e * HDIM + gc];
#pragma unroll
    for (int i = 0; i < 4; i++) {
      const int grb = r0 + wm + i * 16 + crow;
#pragma unroll
      for (int r = 0; r < 4; r++) {
        float v = acc[i][j][r] + bias;
        v = v > 0.f ? v : 0.f;
        hb[(size_t)(grb + r) * HDIM + gc] = __float2bfloat16(v);
      }
    }
  }
}

// ---------------- GEMM2: rowout[r] = h[r] @ W2[e] + b2[e] (bf16), BK=64, swizzled ----------------
__global__ __launch_bounds__(256) void gemm2_kernel(
    const __hip_bfloat16* __restrict__ hb, const __hip_bfloat16* __restrict__ w2t,
    const float* __restrict__ b2, __hip_bfloat16* __restrict__ rowout,
    const int* __restrict__ tile_expert, const int* __restrict__ meta) {
  const int tile_y = blockIdx.y;
  if (tile_y >= meta[0]) return;
  const int n0 = blockIdx.x * 128;
  const int e = tile_expert[tile_y];
  const int r0 = tile_y * 128;
  const int tid = threadIdx.x;
  const int wid = tid >> 6, lane = tid & 63;

  __shared__ __align__(16) __hip_bfloat16 As[128 * 64];
  __shared__ __align__(16) __hip_bfloat16 Bs[128 * 64];

  const int lrow = lane >> 3;
  const int g = ((lane & 7) ^ lrow) * 8;
  const __hip_bfloat16* ga[4]; const __hip_bfloat16* gb[4];
  __hip_bfloat16 *lA[4], *lB[4];
#pragma unroll
  for (int c = 0; c < 4; ++c) {
    const int srow = wid * 32 + c * 8 + lrow;
    ga[c] = hb + ((size_t)r0 + srow) * HDIM + g;
    gb[c] = w2t + ((size_t)e * DDIM + n0 + srow) * HDIM + g;
    lA[c] = &As[(wid * 32 + c * 8) * 64];
    lB[c] = &Bs[(wid * 32 + c * 8) * 64];
  }

  f32x4 acc[4][4] = {};
  const int wm = (wid & 1) * 64, wn = (wid >> 1) * 64;
  const int fr = lane & 15;
  const int swz0 = ((0 + (lane >> 4)) ^ (lane & 7)) * 8;
  const int swz1 = ((4 + (lane >> 4)) ^ (lane & 7)) * 8;

  for (int kt = 0; kt < HDIM / 64; ++kt) {
    __syncthreads();
#pragma unroll
    for (int c = 0; c < 4; ++c) {
      async16(ga[c], lA[c]); async16(gb[c], lB[c]);
      ga[c] += 64; gb[c] += 64;
    }
    __syncthreads();
#pragma unroll
    for (int ks = 0; ks < 2; ++ks) {
      const int off = ks ? swz1 : swz0;
      bf16x8 av[4], bv[4];
#pragma unroll
      for (int i = 0; i < 4; i++) av[i] = *(const bf16x8*)&As[(wm + i * 16 + fr) * 64 + off];
#pragma unroll
      for (int j = 0; j < 4; j++) bv[j] = *(const bf16x8*)&Bs[(wn + j * 16 + fr) * 64 + off];
#pragma unroll
      for (int i = 0; i < 4; i++)
#pragma unroll
        for (int j = 0; j < 4; j++)
          acc[i][j] = __builtin_amdgcn_mfma_f32_16x16x32_bf16(av[i], bv[j], acc[i][j], 0, 0, 0);
    }
  }

  const int crow = (lane >> 4) * 4;
  const int ccol = lane & 15;
#pragma unroll
  for (int j = 0; j < 4; j++) {
    const int gc = n0 + wn + j * 16 + ccol;
    const float bias = b2[e * DDIM + gc];
#pragma unroll
    for (int i = 0; i < 4; i++) {
      const int rr = r0 + wm + i * 16 + crow;
#pragma unroll
      for (int r = 0; r < 4; r++)
        rowout[(size_t)(rr + r) * DDIM + gc] = __float2bfloat16(acc[i][j][r] + bias);
    }
  }
}

// ---------------- combine: out[t] = w0*row0 + w1*row1 ----------------
__global__ __launch_bounds__(256) void combine_kernel(
    const __hip_bfloat16* __restrict__ rowout, const int* __restrict__ tok_row,
    const float* __restrict__ row_weight, float* __restrict__ out) {
  const int idx = blockIdx.x * 256 + threadIdx.x;     // NTOK*128 threads
  const int t = idx >> 7;
  const int d = (idx & 127) * 8;
  const int r0 = tok_row[t * 2 + 0], r1 = tok_row[t * 2 + 1];
  const float w0 = row_weight[r0], w1 = row_weight[r1];
  bf16x8 a = *(const bf16x8*)&rowout[(size_t)r0 * DDIM + d];
  bf16x8 b = *(const bf16x8*)&rowout[(size_t)r1 * DDIM + d];
  float o[8];
#pragma unroll
  for (int k = 0; k < 8; k++) o[k] = w0 * (float)a[k] + w1 * (float)b[k];
  float* dst = out + (size_t)t * DDIM + d;
  *(float4*)(dst + 0) = make_float4(o[0], o[1], o[2], o[3]);
  *(float4*)(dst + 4) = make_float4(o[4], o[5], o[6], o[7]);
}

// ---------------- lb_loss ----------------
__global__ void finalize_kernel(const float* __restrict__ importance,
                                const int* __restrict__ counts, float* __restrict__ lb_out) {
  if (threadIdx.x == 0 && blockIdx.x == 0) {
    float s = 0.f;
    for (int e = 0; e < NEXP; e++) s += importance[e];
    float lb = 0.f;
    for (int e = 0; e < NEXP; e++)
      lb += (importance[e] / s) * ((float)counts[e] / (float)(NTOK * KTOP));
    lb_out[0] = (float)NEXP * lb;
  }
}

// ---------------- launch ----------------
extern "C" void kernel_launch(void* const* d_in, const int* in_sizes, int n_in,
                              void* d_out, int out_size, void* d_ws, size_t ws_size,
                              hipStream_t stream) {
  (void)in_sizes; (void)n_in; (void)out_size; (void)ws_size;
  const float* x  = (const float*)d_in[0];
  const float* Wg = (const float*)d_in[1];
  const float* bg = (const float*)d_in[2];
  const float* W1 = (const float*)d_in[3];
  const float* b1 = (const float*)d_in[4];
  const float* W2 = (const float*)d_in[5];
  const float* b2 = (const float*)d_in[6];
  float* out = (float*)d_out;

  char* ws = (char*)d_ws;
  __hip_bfloat16* xb     = (__hip_bfloat16*)(ws + XB_OFF);
  __hip_bfloat16* w1t    = (__hip_bfloat16*)(ws + W1T_OFF);
  __hip_bfloat16* rowout = (__hip_bfloat16*)(ws + ROWOUT_OFF);
  __hip_bfloat16* w2t    = (__hip_bfloat16*)(ws + W2T_OFF);
  __hip_bfloat16* hb     = (__hip_bfloat16*)(ws + HB_OFF);
  int*   row_token  = (int*)(ws + ROWTOK_OFF);
  float* row_weight = (float*)(ws + ROWW_OFF);
  int*   tok_e   = (int*)(ws + TOKE_OFF);
  float* tok_w   = (float*)(ws + TOKW_OFF);
  int*   tok_row = (int*)(ws + TOKROW_OFF);
  int*   tile_e  = (int*)(ws + TILEE_OFF);
  int*   counts  = (int*)(ws + CNT_OFF);
  int*   pos     = (int*)(ws + POS_OFF);
  float* importance = (float*)(ws + IMP_OFF);
  int*   meta    = (int*)(ws + META_OFF);

  init_kernel<<<1, 64, 0, stream>>>(counts, importance);
  cast_x_kernel<<<NTOK * DDIM / 4 / 256, 256, 0, stream>>>(x, xb);
  transpose_cast_kernel<<<dim3(HDIM / 64, DDIM / 64, NEXP), 256, 0, stream>>>(W1, w1t, DDIM, HDIM);
  transpose_cast_kernel<<<dim3(DDIM / 64, HDIM / 64, NEXP), 256, 0, stream>>>(W2, w2t, HDIM, DDIM);
  gating_kernel<<<NTOK / 32, 256, 0, stream>>>(x, Wg, bg, tok_e, tok_w, counts, importance);
  offsets_kernel<<<1, 256, 0, stream>>>(counts, pos, tile_e, meta, row_token);
  scatter_kernel<<<NTOK / 256, 256, 0, stream>>>(tok_e, tok_w, pos, row_token, row_weight, tok_row);
  gemm1_kernel<<<dim3(HDIM / 128, MAXTILES), 256, 0, stream>>>(xb, w1t, b1, hb, row_token, tile_e, meta);
  gemm2_kernel<<<dim3(DDIM / 128, MAXTILES), 256, 0, stream>>>(hb, w2t, b2, rowout, tile_e, meta);
  combine_kernel<<<NTOK * 128 / 256, 256, 0, stream>>>(rowout, tok_row, row_weight, out);
  finalize_kernel<<<1, 64, 0, stream>>>(importance, counts, out + (size_t)NTOK * DDIM);
}

// Round 3
// 818.828 us; speedup vs baseline: 1.0850x; 1.0520x over previous
//
#include <hip/hip_runtime.h>
#include <hip/hip_bf16.h>
#include <math.h>

#define NTOK 8192
#define DDIM 1024
#define HDIM 4096
#define NEXP 8
#define KTOP 2
#define MAXROWS 17408   /* 16384 + 8*128 */
#define MAXTILES 136

typedef __bf16 bf16x8 __attribute__((ext_vector_type(8)));
typedef float f32x4 __attribute__((ext_vector_type(4)));

#define GAS __attribute__((address_space(1)))
#define LAS __attribute__((address_space(3)))

__device__ __forceinline__ void async16(const void* g, void* l) {
  __builtin_amdgcn_global_load_lds((GAS void*)g, (LAS void*)l, 16, 0, 0);
}

// ---------------- workspace layout (bytes) ----------------
#define XB_OFF     ((size_t)0)
#define W1T_OFF    (XB_OFF + (size_t)NTOK*DDIM*2)
#define ROWOUT_OFF W1T_OFF              /* w1t dead after gemm1; rowout 35.7MB < 64MB */
#define W2T_OFF    (W1T_OFF + (size_t)NEXP*DDIM*HDIM*2)
#define HB_OFF     (W2T_OFF + (size_t)NEXP*HDIM*DDIM*2)
#define ROWTOK_OFF (HB_OFF + (size_t)MAXROWS*HDIM*2)
#define ROWW_OFF   (ROWTOK_OFF + (size_t)MAXROWS*4)
#define TOKE_OFF   (ROWW_OFF + (size_t)MAXROWS*4)
#define TOKW_OFF   (TOKE_OFF + (size_t)NTOK*KTOP*4)
#define TOKROW_OFF (TOKW_OFF + (size_t)NTOK*KTOP*4)
#define TILEE_OFF  (TOKROW_OFF + (size_t)NTOK*KTOP*4)
#define CNT_OFF    (TILEE_OFF + (size_t)256*4)
#define POS_OFF    (CNT_OFF + 64)
#define IMP_OFF    (POS_OFF + 64)
#define META_OFF   (IMP_OFF + 64)

// ---------------- small utility kernels ----------------
__global__ void init_kernel(int* counts, float* importance) {
  if (threadIdx.x < NEXP) { counts[threadIdx.x] = 0; importance[threadIdx.x] = 0.f; }
}

__global__ void cast_x_kernel(const float* __restrict__ src, __hip_bfloat16* __restrict__ dst) {
  size_t i = ((size_t)blockIdx.x * blockDim.x + threadIdx.x) * 4;
  if (i < (size_t)NTOK * DDIM) {
    float4 v = *(const float4*)(src + i);
    dst[i + 0] = __float2bfloat16(v.x);
    dst[i + 1] = __float2bfloat16(v.y);
    dst[i + 2] = __float2bfloat16(v.z);
    dst[i + 3] = __float2bfloat16(v.w);
  }
}

// per-expert transpose+cast: src [E][R][C] fp32 -> dst [E][C][R] bf16
__global__ __launch_bounds__(256) void transpose_cast_kernel(
    const float* __restrict__ src, __hip_bfloat16* __restrict__ dst, int R, int C) {
  __shared__ float tile[64][65];
  const int e = blockIdx.z;
  const float* s = src + (size_t)e * R * C;
  __hip_bfloat16* d = dst + (size_t)e * R * C;
  const int c0 = blockIdx.x * 64, r0 = blockIdx.y * 64;
  const int tc = (threadIdx.x & 15) * 4;
  const int tr = threadIdx.x >> 4;
#pragma unroll
  for (int p = 0; p < 4; ++p) {
    float4 v = *(const float4*)&s[(size_t)(r0 + tr + p * 16) * C + c0 + tc];
    tile[tr + p * 16][tc + 0] = v.x;
    tile[tr + p * 16][tc + 1] = v.y;
    tile[tr + p * 16][tc + 2] = v.z;
    tile[tr + p * 16][tc + 3] = v.w;
  }
  __syncthreads();
  const int oc = threadIdx.x >> 4;
  const int orr = (threadIdx.x & 15) * 4;
#pragma unroll
  for (int p = 0; p < 4; ++p) {
    const int c = oc + p * 16;
    __hip_bfloat16 tmp[4];
    tmp[0] = __float2bfloat16(tile[orr + 0][c]);
    tmp[1] = __float2bfloat16(tile[orr + 1][c]);
    tmp[2] = __float2bfloat16(tile[orr + 2][c]);
    tmp[3] = __float2bfloat16(tile[orr + 3][c]);
    *(ushort4*)&d[(size_t)(c0 + c) * R + r0 + orr] = *(ushort4*)tmp;
  }
}

// ---------------- gating ----------------
__global__ __launch_bounds__(256) void gating_kernel(
    const float* __restrict__ x, const float* __restrict__ Wg, const float* __restrict__ bg,
    int* __restrict__ tok_e, float* __restrict__ tok_w,
    int* __restrict__ counts, float* __restrict__ importance) {
  const int tid = threadIdx.x, wid = tid >> 6, lane = tid & 63;
  const int t = blockIdx.x * 32 + wid * 8 + (lane >> 3);
  const int e = lane & 7;
  const float* xr = x + (size_t)t * DDIM;
  double dot = 0.0;
  for (int d = 0; d < DDIM; d += 4) {
    float4 xv = *(const float4*)(xr + d);
    dot += (double)xv.x * (double)Wg[(d + 0) * NEXP + e];
    dot += (double)xv.y * (double)Wg[(d + 1) * NEXP + e];
    dot += (double)xv.z * (double)Wg[(d + 2) * NEXP + e];
    dot += (double)xv.w * (double)Wg[(d + 3) * NEXP + e];
  }
  double logit = dot + (double)bg[e];
  double m = logit;
  for (int off = 1; off < 8; off <<= 1) {
    double o = __shfl_xor(m, off, 64);
    m = o > m ? o : m;
  }
  double p = exp(logit - m);
  double s = p;
  for (int off = 1; off < 8; off <<= 1) s += __shfl_xor(s, off, 64);
  float prob = (float)(p / s);

  __shared__ float imp[NEXP];
  __shared__ int cnt[NEXP];
  if (tid < NEXP) { imp[tid] = 0.f; cnt[tid] = 0; }
  __syncthreads();
  atomicAdd(&imp[e], prob);

  float bp = prob; int be = e;
  for (int off = 1; off < 8; off <<= 1) {
    float op = __shfl_xor(bp, off, 64); int oe = __shfl_xor(be, off, 64);
    if (op > bp || (op == bp && oe < be)) { bp = op; be = oe; }
  }
  float p2 = (e == be) ? -1.f : prob;
  float sp = p2; int se = e;
  for (int off = 1; off < 8; off <<= 1) {
    float op = __shfl_xor(sp, off, 64); int oe = __shfl_xor(se, off, 64);
    if (op > sp || (op == sp && oe < se)) { sp = op; se = oe; }
  }
  if (e == 0) {
    float tsum = bp + sp;
    tok_e[t * 2 + 0] = be; tok_e[t * 2 + 1] = se;
    tok_w[t * 2 + 0] = bp / tsum; tok_w[t * 2 + 1] = sp / tsum;
    atomicAdd(&cnt[be], 1); atomicAdd(&cnt[se], 1);
  }
  __syncthreads();
  if (tid < NEXP) {
    atomicAdd(&counts[tid], cnt[tid]);
    atomicAdd(&importance[tid], imp[tid]);
  }
}

// ---------------- routing ----------------
__global__ void offsets_kernel(const int* __restrict__ counts, int* pos, int* tile_expert,
                               int* meta, int* row_token) {
  if (threadIdx.x == 0) {
    int pb = 0, tb = 0;
    for (int e = 0; e < NEXP; e++) {
      pos[e] = pb;
      int tiles = (counts[e] + 127) >> 7;
      for (int tt = 0; tt < tiles; ++tt) tile_expert[tb + tt] = e;
      pb += tiles * 128; tb += tiles;
    }
    meta[0] = tb;
  }
  __syncthreads();
  for (int i = threadIdx.x; i < MAXROWS; i += blockDim.x) row_token[i] = -1;
}

__global__ void scatter_kernel(const int* __restrict__ tok_e, const float* __restrict__ tok_w,
                               int* __restrict__ pos, int* __restrict__ row_token,
                               float* __restrict__ row_weight, int* __restrict__ tok_row) {
  __shared__ int lcnt[NEXP], lbase[NEXP];
  const int t = blockIdx.x * 256 + threadIdx.x;
  if (threadIdx.x < NEXP) lcnt[threadIdx.x] = 0;
  __syncthreads();
  const int e0 = tok_e[t * 2 + 0], e1 = tok_e[t * 2 + 1];
  const int s0 = atomicAdd(&lcnt[e0], 1);
  const int s1 = atomicAdd(&lcnt[e1], 1);
  __syncthreads();
  if (threadIdx.x < NEXP) lbase[threadIdx.x] = atomicAdd(&pos[threadIdx.x], lcnt[threadIdx.x]);
  __syncthreads();
  int r0 = lbase[e0] + s0; row_token[r0] = t; row_weight[r0] = tok_w[t * 2 + 0]; tok_row[t * 2 + 0] = r0;
  int r1 = lbase[e1] + s1; row_token[r1] = t; row_weight[r1] = tok_w[t * 2 + 1]; tok_row[t * 2 + 1] = r1;
}

// ---------------- GEMM1: h = relu(x @ W1[e] + b1[e]), BK=32, double-buffered ----------------
__global__ __launch_bounds__(256) void gemm1_kernel(
    const __hip_bfloat16* __restrict__ xb, const __hip_bfloat16* __restrict__ w1t,
    const float* __restrict__ b1, __hip_bfloat16* __restrict__ hb,
    const int* __restrict__ row_token, const int* __restrict__ tile_expert,
    const int* __restrict__ meta) {
  const int tile_y = blockIdx.y;
  if (tile_y >= meta[0]) return;
  const int n0 = blockIdx.x * 128;
  const int e = tile_expert[tile_y];
  const int r0 = tile_y * 128;
  const int tid = threadIdx.x;
  const int wid = tid >> 6, lane = tid & 63;

  __shared__ __align__(16) __hip_bfloat16 As[2][128 * 32];
  __shared__ __align__(16) __hip_bfloat16 Bs[2][128 * 32];

  const int srow = wid * 32 + (lane >> 2);
  const int g = ((lane & 3) ^ (srow & 3)) * 8;   // swizzled 16B group (elements)
  int t0 = row_token[r0 + srow];      if (t0 < 0) t0 = 0;
  int t1 = row_token[r0 + srow + 16]; if (t1 < 0) t1 = 0;
  const __hip_bfloat16* ga0 = xb + (size_t)t0 * DDIM + g;
  const __hip_bfloat16* ga1 = xb + (size_t)t1 * DDIM + g;
  const __hip_bfloat16* gb0 = w1t + ((size_t)e * HDIM + n0 + srow) * DDIM + g;
  const __hip_bfloat16* gb1 = gb0 + (size_t)16 * DDIM;
  const int ldsA0 = (wid * 32) * 32, ldsA1 = (wid * 32 + 16) * 32;

  f32x4 acc[4][4] = {};
  const int wm = (wid & 1) * 64, wn = (wid >> 1) * 64;
  const int fr = lane & 15;
  const int soff = ((lane >> 4) ^ (lane & 3)) * 8;

#define STAGE1(b) do { \
    async16(ga0, &As[b][ldsA0]); async16(ga1, &As[b][ldsA1]); \
    async16(gb0, &Bs[b][ldsA0]); async16(gb1, &Bs[b][ldsA1]); \
    ga0 += 32; ga1 += 32; gb0 += 32; gb1 += 32; } while (0)

  STAGE1(0);
  for (int kt = 0; kt < DDIM / 32; ++kt) {
    const int cur = kt & 1;
    __syncthreads();              // vmcnt(0) drain: tile kt resident; prior reads done
    if (kt + 1 < DDIM / 32) { if (cur) STAGE1(0); else STAGE1(1); }
    bf16x8 av[4], bv[4];
#pragma unroll
    for (int i = 0; i < 4; i++) av[i] = *(const bf16x8*)&As[cur][(wm + i * 16 + fr) * 32 + soff];
#pragma unroll
    for (int j = 0; j < 4; j++) bv[j] = *(const bf16x8*)&Bs[cur][(wn + j * 16 + fr) * 32 + soff];
#pragma unroll
    for (int i = 0; i < 4; i++)
#pragma unroll
      for (int j = 0; j < 4; j++)
        acc[i][j] = __builtin_amdgcn_mfma_f32_16x16x32_bf16(av[i], bv[j], acc[i][j], 0, 0, 0);
  }
#undef STAGE1

  const int crow = (lane >> 4) * 4;
  const int ccol = lane & 15;
#pragma unroll
  for (int j = 0; j < 4; j++) {
    const int gc = n0 + wn + j * 16 + ccol;
    const float bias = b1[e * HDIM + gc];
#pragma unroll
    for (int i = 0; i < 4; i++) {
      const int grb = r0 + wm + i * 16 + crow;
#pragma unroll
      for (int r = 0; r < 4; r++) {
        float v = acc[i][j][r] + bias;
        v = v > 0.f ? v : 0.f;
        hb[(size_t)(grb + r) * HDIM + gc] = __float2bfloat16(v);
      }
    }
  }
}

// ---------------- GEMM2: rowout[r] = h[r] @ W2[e] + b2[e], BK=32, dbuf, XCD-swizzled ----------------
__global__ __launch_bounds__(256) void gemm2_kernel(
    const __hip_bfloat16* __restrict__ hb, const __hip_bfloat16* __restrict__ w2t,
    const float* __restrict__ b2, __hip_bfloat16* __restrict__ rowout,
    const int* __restrict__ tile_expert, const int* __restrict__ meta) {
  // 1D grid, MAXTILES%8==0: all 8 column-blocks of a row-tile share id%8 -> same XCD
  const int tile_y = blockIdx.x % MAXTILES;
  const int cx = blockIdx.x / MAXTILES;
  if (tile_y >= meta[0]) return;
  const int n0 = cx * 128;
  const int e = tile_expert[tile_y];
  const int r0 = tile_y * 128;
  const int tid = threadIdx.x;
  const int wid = tid >> 6, lane = tid & 63;

  __shared__ __align__(16) __hip_bfloat16 As[2][128 * 32];
  __shared__ __align__(16) __hip_bfloat16 Bs[2][128 * 32];

  const int srow = wid * 32 + (lane >> 2);
  const int g = ((lane & 3) ^ (srow & 3)) * 8;
  const __hip_bfloat16* ga0 = hb + ((size_t)r0 + srow) * HDIM + g;
  const __hip_bfloat16* ga1 = ga0 + (size_t)16 * HDIM;
  const __hip_bfloat16* gb0 = w2t + ((size_t)e * DDIM + n0 + srow) * HDIM + g;
  const __hip_bfloat16* gb1 = gb0 + (size_t)16 * HDIM;
  const int ldsA0 = (wid * 32) * 32, ldsA1 = (wid * 32 + 16) * 32;

  f32x4 acc[4][4] = {};
  const int wm = (wid & 1) * 64, wn = (wid >> 1) * 64;
  const int fr = lane & 15;
  const int soff = ((lane >> 4) ^ (lane & 3)) * 8;

#define STAGE2(b) do { \
    async16(ga0, &As[b][ldsA0]); async16(ga1, &As[b][ldsA1]); \
    async16(gb0, &Bs[b][ldsA0]); async16(gb1, &Bs[b][ldsA1]); \
    ga0 += 32; ga1 += 32; gb0 += 32; gb1 += 32; } while (0)

  STAGE2(0);
  for (int kt = 0; kt < HDIM / 32; ++kt) {
    const int cur = kt & 1;
    __syncthreads();
    if (kt + 1 < HDIM / 32) { if (cur) STAGE2(0); else STAGE2(1); }
    bf16x8 av[4], bv[4];
#pragma unroll
    for (int i = 0; i < 4; i++) av[i] = *(const bf16x8*)&As[cur][(wm + i * 16 + fr) * 32 + soff];
#pragma unroll
    for (int j = 0; j < 4; j++) bv[j] = *(const bf16x8*)&Bs[cur][(wn + j * 16 + fr) * 32 + soff];
#pragma unroll
    for (int i = 0; i < 4; i++)
#pragma unroll
      for (int j = 0; j < 4; j++)
        acc[i][j] = __builtin_amdgcn_mfma_f32_16x16x32_bf16(av[i], bv[j], acc[i][j], 0, 0, 0);
  }
#undef STAGE2

  const int crow = (lane >> 4) * 4;
  const int ccol = lane & 15;
#pragma unroll
  for (int j = 0; j < 4; j++) {
    const int gc = n0 + wn + j * 16 + ccol;
    const float bias = b2[e * DDIM + gc];
#pragma unroll
    for (int i = 0; i < 4; i++) {
      const int rr = r0 + wm + i * 16 + crow;
#pragma unroll
      for (int r = 0; r < 4; r++)
        rowout[(size_t)(rr + r) * DDIM + gc] = __float2bfloat16(acc[i][j][r] + bias);
    }
  }
}

// ---------------- combine: out[t] = w0*row0 + w1*row1 ----------------
__global__ __launch_bounds__(256) void combine_kernel(
    const __hip_bfloat16* __restrict__ rowout, const int* __restrict__ tok_row,
    const float* __restrict__ row_weight, float* __restrict__ out) {
  const int idx = blockIdx.x * 256 + threadIdx.x;
  const int t = idx >> 7;
  const int d = (idx & 127) * 8;
  const int r0 = tok_row[t * 2 + 0], r1 = tok_row[t * 2 + 1];
  const float w0 = row_weight[r0], w1 = row_weight[r1];
  bf16x8 a = *(const bf16x8*)&rowout[(size_t)r0 * DDIM + d];
  bf16x8 b = *(const bf16x8*)&rowout[(size_t)r1 * DDIM + d];
  float o[8];
#pragma unroll
  for (int k = 0; k < 8; k++) o[k] = w0 * (float)a[k] + w1 * (float)b[k];
  float* dst = out + (size_t)t * DDIM + d;
  *(float4*)(dst + 0) = make_float4(o[0], o[1], o[2], o[3]);
  *(float4*)(dst + 4) = make_float4(o[4], o[5], o[6], o[7]);
}

// ---------------- lb_loss ----------------
__global__ void finalize_kernel(const float* __restrict__ importance,
                                const int* __restrict__ counts, float* __restrict__ lb_out) {
  if (threadIdx.x == 0 && blockIdx.x == 0) {
    float s = 0.f;
    for (int e = 0; e < NEXP; e++) s += importance[e];
    float lb = 0.f;
    for (int e = 0; e < NEXP; e++)
      lb += (importance[e] / s) * ((float)counts[e] / (float)(NTOK * KTOP));
    lb_out[0] = (float)NEXP * lb;
  }
}

// ---------------- launch ----------------
extern "C" void kernel_launch(void* const* d_in, const int* in_sizes, int n_in,
                              void* d_out, int out_size, void* d_ws, size_t ws_size,
                              hipStream_t stream) {
  (void)in_sizes; (void)n_in; (void)out_size; (void)ws_size;
  const float* x  = (const float*)d_in[0];
  const float* Wg = (const float*)d_in[1];
  const float* bg = (const float*)d_in[2];
  const float* W1 = (const float*)d_in[3];
  const float* b1 = (const float*)d_in[4];
  const float* W2 = (const float*)d_in[5];
  const float* b2 = (const float*)d_in[6];
  float* out = (float*)d_out;

  char* ws = (char*)d_ws;
  __hip_bfloat16* xb     = (__hip_bfloat16*)(ws + XB_OFF);
  __hip_bfloat16* w1t    = (__hip_bfloat16*)(ws + W1T_OFF);
  __hip_bfloat16* rowout = (__hip_bfloat16*)(ws + ROWOUT_OFF);
  __hip_bfloat16* w2t    = (__hip_bfloat16*)(ws + W2T_OFF);
  __hip_bfloat16* hb     = (__hip_bfloat16*)(ws + HB_OFF);
  int*   row_token  = (int*)(ws + ROWTOK_OFF);
  float* row_weight = (float*)(ws + ROWW_OFF);
  int*   tok_e   = (int*)(ws + TOKE_OFF);
  float* tok_w   = (float*)(ws + TOKW_OFF);
  int*   tok_row = (int*)(ws + TOKROW_OFF);
  int*   tile_e  = (int*)(ws + TILEE_OFF);
  int*   counts  = (int*)(ws + CNT_OFF);
  int*   pos     = (int*)(ws + POS_OFF);
  float* importance = (float*)(ws + IMP_OFF);
  int*   meta    = (int*)(ws + META_OFF);

  init_kernel<<<1, 64, 0, stream>>>(counts, importance);
  cast_x_kernel<<<NTOK * DDIM / 4 / 256, 256, 0, stream>>>(x, xb);
  transpose_cast_kernel<<<dim3(HDIM / 64, DDIM / 64, NEXP), 256, 0, stream>>>(W1, w1t, DDIM, HDIM);
  transpose_cast_kernel<<<dim3(DDIM / 64, HDIM / 64, NEXP), 256, 0, stream>>>(W2, w2t, HDIM, DDIM);
  gating_kernel<<<NTOK / 32, 256, 0, stream>>>(x, Wg, bg, tok_e, tok_w, counts, importance);
  offsets_kernel<<<1, 256, 0, stream>>>(counts, pos, tile_e, meta, row_token);
  scatter_kernel<<<NTOK / 256, 256, 0, stream>>>(tok_e, tok_w, pos, row_token, row_weight, tok_row);
  gemm1_kernel<<<dim3(HDIM / 128, MAXTILES), 256, 0, stream>>>(xb, w1t, b1, hb, row_token, tile_e, meta);
  gemm2_kernel<<<dim3((DDIM / 128) * MAXTILES), 256, 0, stream>>>(hb, w2t, b2, rowout, tile_e, meta);
  combine_kernel<<<NTOK * 128 / 256, 256, 0, stream>>>(rowout, tok_row, row_weight, out);
  finalize_kernel<<<1, 64, 0, stream>>>(importance, counts, out + (size_t)NTOK * DDIM);
}